// Round 3
// baseline (428.818 us; speedup 1.0000x reference)
//
#include <hip/hip_runtime.h>

// Mamba selective scan, single fused kernel with grid-wide barrier.
//   h_t = exp(delta_t * A) * h_{t-1} + delta_t * B_t * x_t
//   y_t = sum_n h_t[n] * C_t[n] + D * x_t
// Phase A: per-chunk local scan from zero -> Q (chunk-exit state), Dsum(=sum delta)
//          [chunk decay product = exp2(A*log2e * Dsum) -- a SUM, so the combine
//           needs no per-element product of exps]
// Phase B: distributed inter-chunk serial scan (one wave per block) -> Hprev
// Phase C: re-scan seeded with Hprev, fused C-contraction + D*x epilogue -> y
// Grid = 512 blocks x 256 thr = exactly 2 blocks/CU on 256 CUs; launch_bounds
// caps VGPR at 256 so co-residency (and thus the barrier) is guaranteed.

#define LOG2E 1.4426950408889634f

#if __has_builtin(__builtin_amdgcn_exp2f)
#define EXP2F(xx) __builtin_amdgcn_exp2f(xx)
#else
#define EXP2F(xx) exp2f(xx)
#endif

constexpr int BATCH = 2;
constexpr int SEQ   = 2048;
constexpr int ED    = 1024;
constexpr int NS    = 16;

constexpr int NC  = 64;          // chunks
constexpr int CT  = SEQ / NC;    // 32 timesteps/chunk
constexpr int EDG = 256;         // ed channels per block
constexpr int NEG = ED / EDG;    // 4
constexpr int NBLK = NC * NEG * BATCH;  // 512 blocks

__device__ unsigned g_count = 0;
__device__ unsigned g_gen   = 0;

__device__ __forceinline__ void grid_barrier(int tid) {
    __threadfence();              // release: publish this block's global writes
    __syncthreads();
    if (tid == 0) {
        unsigned gen = __hip_atomic_load(&g_gen, __ATOMIC_RELAXED, __HIP_MEMORY_SCOPE_AGENT);
        unsigned t = __hip_atomic_fetch_add(&g_count, 1u, __ATOMIC_ACQ_REL, __HIP_MEMORY_SCOPE_AGENT);
        if (t == (unsigned)(NBLK - 1)) {
            __hip_atomic_store(&g_count, 0u, __ATOMIC_RELAXED, __HIP_MEMORY_SCOPE_AGENT);
            __hip_atomic_store(&g_gen, gen + 1u, __ATOMIC_RELEASE, __HIP_MEMORY_SCOPE_AGENT);
        } else {
            while (__hip_atomic_load(&g_gen, __ATOMIC_ACQUIRE, __HIP_MEMORY_SCOPE_AGENT) == gen) {
                __builtin_amdgcn_s_sleep(4);
            }
        }
    }
    __syncthreads();
    __threadfence();              // acquire: see other blocks' writes
}

__global__ __launch_bounds__(EDG, 2) void ssm_fused(
    const float* __restrict__ x, const float* __restrict__ dl,
    const float* __restrict__ A, const float* __restrict__ B,
    const float* __restrict__ C, const float* __restrict__ Dv,
    float* __restrict__ Q, float* __restrict__ Dsum,
    float* __restrict__ Hprev, float* __restrict__ y)
{
    const int c = blockIdx.x, g = blockIdx.y, b = blockIdx.z;
    const int tid = threadIdx.x;
    const int ed = g * EDG + tid;
    const int fb = c + NC * (g + NEG * b);   // flat block id in [0, 512)

    __shared__ alignas(16) float Bs[CT * NS];   // 2 KB
    __shared__ alignas(16) float Cs[CT * NS];   // 2 KB
    const long tbase = (long)b * SEQ + (long)c * CT;
    for (int i = tid; i < CT * NS; i += EDG) {
        Bs[i] = B[tbase * NS + i];
        Cs[i] = C[tbase * NS + i];
    }
    __syncthreads();

    float A2[NS];
    {
        const float4* Ap = reinterpret_cast<const float4*>(A + (long)ed * NS);
        #pragma unroll
        for (int k = 0; k < 4; ++k) {
            float4 a4 = Ap[k];
            A2[4*k+0] = a4.x * LOG2E; A2[4*k+1] = a4.y * LOG2E;
            A2[4*k+2] = a4.z * LOG2E; A2[4*k+3] = a4.w * LOG2E;
        }
    }

    const float* dp = dl + tbase * ED + ed;
    const float* xp = x  + tbase * ED + ed;

    // ---------------- phase A: chunk-local scan from zero ----------------
    {
        float h[NS];
        #pragma unroll
        for (int n = 0; n < NS; ++n) h[n] = 0.f;
        float dsum = 0.f;

        #pragma unroll 4
        for (int t = 0; t < CT; ++t) {
            float dlt = dp[(long)t * ED];
            float xv  = xp[(long)t * ED];
            dsum += dlt;
            float dx = dlt * xv;
            const float4* Bs4 = reinterpret_cast<const float4*>(&Bs[t * NS]);
            #pragma unroll
            for (int k = 0; k < 4; ++k) {
                float4 b4 = Bs4[k];
                h[4*k+0] = fmaf(EXP2F(dlt * A2[4*k+0]), h[4*k+0], dx * b4.x);
                h[4*k+1] = fmaf(EXP2F(dlt * A2[4*k+1]), h[4*k+1], dx * b4.y);
                h[4*k+2] = fmaf(EXP2F(dlt * A2[4*k+2]), h[4*k+2], dx * b4.z);
                h[4*k+3] = fmaf(EXP2F(dlt * A2[4*k+3]), h[4*k+3], dx * b4.w);
            }
        }

        const long qo = ((long)(c * BATCH + b) * ED + ed) * NS;
        float4* Qp = reinterpret_cast<float4*>(Q + qo);
        #pragma unroll
        for (int k = 0; k < 4; ++k)
            Qp[k] = make_float4(h[4*k+0], h[4*k+1], h[4*k+2], h[4*k+3]);
        Dsum[(long)(c * BATCH + b) * ED + ed] = dsum;
    }

    grid_barrier(tid);

    // ---------------- phase B: inter-chunk scan (1 wave / block) ----------------
    if (tid < 64) {
        const int item = fb * 64 + tid;        // (b2*ED + e2)*16 + n
        const int n  = item & (NS - 1);
        const int e2 = (item >> 4) & (ED - 1);
        const int b2 = item >> 14;
        const float a2 = A[(long)e2 * NS + n] * LOG2E;
        float hh = 0.f;
        float ds = Dsum[(long)(0 * BATCH + b2) * ED + e2];
        float qv = Q[((long)(0 * BATCH + b2) * ED + e2) * NS + n];
        #pragma unroll 4
        for (int cc = 0; cc < NC; ++cc) {
            const long o = ((long)(cc * BATCH + b2) * ED + e2) * NS + n;
            Hprev[o] = hh;
            float P = EXP2F(a2 * ds);
            hh = fmaf(P, hh, qv);
            if (cc + 1 < NC) {   // prefetch next chunk's summary
                ds = Dsum[(long)((cc + 1) * BATCH + b2) * ED + e2];
                qv = Q[((long)((cc + 1) * BATCH + b2) * ED + e2) * NS + n];
            }
        }
    }

    grid_barrier(tid);

    // ---------------- phase C: seeded re-scan + fused epilogue ----------------
    {
        float h[NS];
        {
            const long qo = ((long)(c * BATCH + b) * ED + ed) * NS;
            const float4* Hp = reinterpret_cast<const float4*>(Hprev + qo);
            #pragma unroll
            for (int k = 0; k < 4; ++k) {
                float4 h4 = Hp[k];
                h[4*k+0] = h4.x; h[4*k+1] = h4.y; h[4*k+2] = h4.z; h[4*k+3] = h4.w;
            }
        }
        const float dvec = Dv[ed];
        float* yp = y + tbase * ED + ed;

        #pragma unroll 4
        for (int t = 0; t < CT; ++t) {
            float dlt = dp[(long)t * ED];
            float xv  = xp[(long)t * ED];
            float dx = dlt * xv;
            float acc = dvec * xv;
            const float4* Bs4 = reinterpret_cast<const float4*>(&Bs[t * NS]);
            const float4* Cs4 = reinterpret_cast<const float4*>(&Cs[t * NS]);
            #pragma unroll
            for (int k = 0; k < 4; ++k) {
                float4 b4 = Bs4[k];
                float4 c4 = Cs4[k];
                h[4*k+0] = fmaf(EXP2F(dlt * A2[4*k+0]), h[4*k+0], dx * b4.x);
                acc = fmaf(h[4*k+0], c4.x, acc);
                h[4*k+1] = fmaf(EXP2F(dlt * A2[4*k+1]), h[4*k+1], dx * b4.y);
                acc = fmaf(h[4*k+1], c4.y, acc);
                h[4*k+2] = fmaf(EXP2F(dlt * A2[4*k+2]), h[4*k+2], dx * b4.z);
                acc = fmaf(h[4*k+2], c4.z, acc);
                h[4*k+3] = fmaf(EXP2F(dlt * A2[4*k+3]), h[4*k+3], dx * b4.w);
                acc = fmaf(h[4*k+3], c4.w, acc);
            }
            yp[(long)t * ED] = acc;
        }
    }
}

// ---------------- fallback (tiny workspace): fully sequential ----------------
__global__ __launch_bounds__(EDG) void ssm_fallback(
    const float* __restrict__ x, const float* __restrict__ dl,
    const float* __restrict__ A, const float* __restrict__ B,
    const float* __restrict__ C, const float* __restrict__ Dv,
    float* __restrict__ y)
{
    const int g = blockIdx.x, b = blockIdx.y;
    const int ed = g * EDG + threadIdx.x;

    float A2[NS];
    {
        const float4* Ap = reinterpret_cast<const float4*>(A + (long)ed * NS);
        #pragma unroll
        for (int k = 0; k < 4; ++k) {
            float4 a4 = Ap[k];
            A2[4*k+0] = a4.x * LOG2E; A2[4*k+1] = a4.y * LOG2E;
            A2[4*k+2] = a4.z * LOG2E; A2[4*k+3] = a4.w * LOG2E;
        }
    }
    float h[NS];
    #pragma unroll
    for (int n = 0; n < NS; ++n) h[n] = 0.f;
    const float dvec = Dv[ed];

    for (int t = 0; t < SEQ; ++t) {
        const long tb = (long)b * SEQ + t;
        float dlt = dl[tb * ED + ed];
        float xv  = x[tb * ED + ed];
        float dx = dlt * xv;
        float acc = dvec * xv;
        const float4* Bp = reinterpret_cast<const float4*>(B + tb * NS);
        const float4* Cp = reinterpret_cast<const float4*>(C + tb * NS);
        #pragma unroll
        for (int k = 0; k < 4; ++k) {
            float4 b4 = Bp[k];
            float4 c4 = Cp[k];
            h[4*k+0] = fmaf(EXP2F(dlt * A2[4*k+0]), h[4*k+0], dx * b4.x);
            acc = fmaf(h[4*k+0], c4.x, acc);
            h[4*k+1] = fmaf(EXP2F(dlt * A2[4*k+1]), h[4*k+1], dx * b4.y);
            acc = fmaf(h[4*k+1], c4.y, acc);
            h[4*k+2] = fmaf(EXP2F(dlt * A2[4*k+2]), h[4*k+2], dx * b4.z);
            acc = fmaf(h[4*k+2], c4.z, acc);
            h[4*k+3] = fmaf(EXP2F(dlt * A2[4*k+3]), h[4*k+3], dx * b4.w);
            acc = fmaf(h[4*k+3], c4.w, acc);
        }
        y[tb * ED + ed] = acc;
    }
}

extern "C" void kernel_launch(void* const* d_in, const int* in_sizes, int n_in,
                              void* d_out, int out_size, void* d_ws, size_t ws_size,
                              hipStream_t stream) {
    const float* x  = (const float*)d_in[0];
    const float* dl = (const float*)d_in[1];
    const float* A  = (const float*)d_in[2];
    const float* B  = (const float*)d_in[3];
    const float* C  = (const float*)d_in[4];
    const float* Dv = (const float*)d_in[5];
    float* y = (float*)d_out;

    const size_t qElems = (size_t)NC * BATCH * ED * NS;   // 2M floats
    const size_t dElems = (size_t)NC * BATCH * ED;        // 128K floats
    const size_t need = (2 * qElems + dElems) * sizeof(float);  // ~16.5 MB

    if (ws_size >= need) {
        float* Q     = (float*)d_ws;
        float* Hprev = Q + qElems;
        float* Dsum  = Hprev + qElems;
        ssm_fused<<<dim3(NC, NEG, BATCH), EDG, 0, stream>>>(
            x, dl, A, B, C, Dv, Q, Dsum, Hprev, y);
    } else {
        ssm_fallback<<<dim3(NEG, BATCH), EDG, 0, stream>>>(x, dl, A, B, C, Dv, y);
    }
}

// Round 5
// 114.339 us; speedup vs baseline: 3.7504x; 3.7504x over previous
//
#include <hip/hip_runtime.h>

// Mamba selective scan, 3 stream-ordered dispatches (no grid barrier: cross-XCD
// fences on MI355X cost ~300us -- measured round 3).
//   h_t = exp(delta_t * A) * h_{t-1} + delta_t * B_t * x_t
//   y_t = sum_n h_t[n] * C_t[n] + D * x_t
// Pass 1: per-chunk local scan from zero -> Q (chunk-exit state), Dsum (=sum delta)
//         [chunk decay product = exp2(A*log2e * Dsum): a SUM of deltas, so the
//          inter-chunk combine needs no per-element exp products]
// Pass 2: inter-chunk scan -> Hprev. Key: P_cc = exp2(a2*Dsum_cc) is independent
//         of the chain; only 64 fmas are serial. Grouped-8 with prefetch.
// Pass 3: re-scan seeded with Hprev, fused C-contraction + D*x epilogue -> y.
//         x/delta re-reads are L3-resident (FETCH measured ~44MB << 2x inputs).

#define LOG2E 1.4426950408889634f

#if __has_builtin(__builtin_amdgcn_exp2f)
#define EXP2F(xx) __builtin_amdgcn_exp2f(xx)
#else
#define EXP2F(xx) exp2f(xx)
#endif

constexpr int BATCH = 2;
constexpr int SEQ   = 2048;
constexpr int ED    = 1024;
constexpr int NS    = 16;

constexpr int NC  = 64;          // chunks
constexpr int CT  = SEQ / NC;    // 32 timesteps/chunk
constexpr int EDG = 256;         // ed channels per block
constexpr int NEG = ED / EDG;    // 4

// ---------------- pass 1: chunk-local scan ----------------
__global__ __launch_bounds__(EDG, 2) void ssm_pass1(
    const float* __restrict__ x, const float* __restrict__ dl,
    const float* __restrict__ A, const float* __restrict__ B,
    float* __restrict__ Q, float* __restrict__ Dsum)
{
    const int c = blockIdx.x, g = blockIdx.y, b = blockIdx.z;
    const int tid = threadIdx.x;
    const int ed = g * EDG + tid;

    __shared__ alignas(16) float Bs[CT * NS];   // 2 KB
    const long tbase = (long)b * SEQ + (long)c * CT;
    for (int i = tid; i < CT * NS; i += EDG) Bs[i] = B[tbase * NS + i];
    __syncthreads();

    float A2[NS];
    {
        const float4* Ap = reinterpret_cast<const float4*>(A + (long)ed * NS);
        #pragma unroll
        for (int k = 0; k < 4; ++k) {
            float4 a4 = Ap[k];
            A2[4*k+0] = a4.x * LOG2E; A2[4*k+1] = a4.y * LOG2E;
            A2[4*k+2] = a4.z * LOG2E; A2[4*k+3] = a4.w * LOG2E;
        }
    }

    float h[NS];
    #pragma unroll
    for (int n = 0; n < NS; ++n) h[n] = 0.f;
    float dsum = 0.f;

    const float* dp = dl + tbase * ED + ed;
    const float* xp = x  + tbase * ED + ed;

    // software pipeline: group-of-4, one group of loads ahead (8 loads in flight)
    float da[4], xa[4];
    #pragma unroll
    for (int j = 0; j < 4; ++j) { da[j] = dp[(long)j * ED]; xa[j] = xp[(long)j * ED]; }

    for (int tg = 0; tg < CT / 4; ++tg) {
        float dn[4], xn[4];
        if (tg < CT / 4 - 1) {
            #pragma unroll
            for (int j = 0; j < 4; ++j) {
                dn[j] = dp[(long)((tg + 1) * 4 + j) * ED];
                xn[j] = xp[(long)((tg + 1) * 4 + j) * ED];
            }
        }
        #pragma unroll
        for (int j = 0; j < 4; ++j) {
            const int t = tg * 4 + j;
            float dlt = da[j], xv = xa[j];
            dsum += dlt;
            float dx = dlt * xv;
            const float4* Bs4 = reinterpret_cast<const float4*>(&Bs[t * NS]);
            #pragma unroll
            for (int k = 0; k < 4; ++k) {
                float4 b4 = Bs4[k];
                h[4*k+0] = fmaf(EXP2F(dlt * A2[4*k+0]), h[4*k+0], dx * b4.x);
                h[4*k+1] = fmaf(EXP2F(dlt * A2[4*k+1]), h[4*k+1], dx * b4.y);
                h[4*k+2] = fmaf(EXP2F(dlt * A2[4*k+2]), h[4*k+2], dx * b4.z);
                h[4*k+3] = fmaf(EXP2F(dlt * A2[4*k+3]), h[4*k+3], dx * b4.w);
            }
        }
        #pragma unroll
        for (int j = 0; j < 4; ++j) { da[j] = dn[j]; xa[j] = xn[j]; }
    }

    const long qo = ((long)(c * BATCH + b) * ED + ed) * NS;
    float4* Qp = reinterpret_cast<float4*>(Q + qo);
    #pragma unroll
    for (int k = 0; k < 4; ++k)
        Qp[k] = make_float4(h[4*k+0], h[4*k+1], h[4*k+2], h[4*k+3]);
    Dsum[(long)(c * BATCH + b) * ED + ed] = dsum;
}

// ---------------- pass 2: inter-chunk scan ----------------
// One thread per (b, ed, n): 32768 items = 256 blocks x 128 threads (1 block/CU).
// P factors are chain-independent -> grouped-8 prefetch + 8 exps, then 8 fmas.
__global__ __launch_bounds__(128) void ssm_pass2(
    const float* __restrict__ A, const float* __restrict__ Q,
    const float* __restrict__ Dsum, float* __restrict__ Hprev)
{
    const int idx = blockIdx.x * 128 + threadIdx.x;
    const int n  = idx & (NS - 1);
    const int ed = (idx >> 4) & (ED - 1);
    const int b  = idx >> 14;

    const float a2 = A[(long)ed * NS + n] * LOG2E;
    const long strideQ = (long)BATCH * ED * NS;
    const long strideD = (long)BATCH * ED;
    const long o0 = ((long)b * ED + ed) * NS + n;
    const long d0 = (long)b * ED + ed;

    float h = 0.f;
    float qs[8], ds[8];
    #pragma unroll
    for (int j = 0; j < 8; ++j) {
        qs[j] = Q[o0 + (long)j * strideQ];
        ds[j] = Dsum[d0 + (long)j * strideD];
    }
    for (int gi = 0; gi < NC / 8; ++gi) {
        float qn[8], dn[8];
        if (gi < NC / 8 - 1) {
            #pragma unroll
            for (int j = 0; j < 8; ++j) {
                qn[j] = Q[o0 + (long)((gi + 1) * 8 + j) * strideQ];
                dn[j] = Dsum[d0 + (long)((gi + 1) * 8 + j) * strideD];
            }
        }
        float ps[8];
        #pragma unroll
        for (int j = 0; j < 8; ++j) ps[j] = EXP2F(a2 * ds[j]);
        #pragma unroll
        for (int j = 0; j < 8; ++j) {
            Hprev[o0 + (long)(gi * 8 + j) * strideQ] = h;   // state BEFORE chunk
            h = fmaf(ps[j], h, qs[j]);
        }
        #pragma unroll
        for (int j = 0; j < 8; ++j) { qs[j] = qn[j]; ds[j] = dn[j]; }
    }
}

// ---------------- pass 3: seeded re-scan + fused epilogue ----------------
__global__ __launch_bounds__(EDG, 2) void ssm_pass3(
    const float* __restrict__ x, const float* __restrict__ dl,
    const float* __restrict__ A, const float* __restrict__ B,
    const float* __restrict__ C, const float* __restrict__ Dv,
    const float* __restrict__ Hprev, float* __restrict__ y)
{
    const int c = blockIdx.x, g = blockIdx.y, b = blockIdx.z;
    const int tid = threadIdx.x;
    const int ed = g * EDG + tid;

    __shared__ alignas(16) float Bs[CT * NS];
    __shared__ alignas(16) float Cs[CT * NS];
    const long tbase = (long)b * SEQ + (long)c * CT;
    for (int i = tid; i < CT * NS; i += EDG) {
        Bs[i] = B[tbase * NS + i];
        Cs[i] = C[tbase * NS + i];
    }
    __syncthreads();

    float A2[NS];
    {
        const float4* Ap = reinterpret_cast<const float4*>(A + (long)ed * NS);
        #pragma unroll
        for (int k = 0; k < 4; ++k) {
            float4 a4 = Ap[k];
            A2[4*k+0] = a4.x * LOG2E; A2[4*k+1] = a4.y * LOG2E;
            A2[4*k+2] = a4.z * LOG2E; A2[4*k+3] = a4.w * LOG2E;
        }
    }

    float h[NS];
    {
        const long qo = ((long)(c * BATCH + b) * ED + ed) * NS;
        const float4* Hp = reinterpret_cast<const float4*>(Hprev + qo);
        #pragma unroll
        for (int k = 0; k < 4; ++k) {
            float4 h4 = Hp[k];
            h[4*k+0] = h4.x; h[4*k+1] = h4.y; h[4*k+2] = h4.z; h[4*k+3] = h4.w;
        }
    }
    const float dvec = Dv[ed];

    const float* dp = dl + tbase * ED + ed;
    const float* xp = x  + tbase * ED + ed;
    float* yp = y + tbase * ED + ed;

    float da[4], xa[4];
    #pragma unroll
    for (int j = 0; j < 4; ++j) { da[j] = dp[(long)j * ED]; xa[j] = xp[(long)j * ED]; }

    for (int tg = 0; tg < CT / 4; ++tg) {
        float dn[4], xn[4];
        if (tg < CT / 4 - 1) {
            #pragma unroll
            for (int j = 0; j < 4; ++j) {
                dn[j] = dp[(long)((tg + 1) * 4 + j) * ED];
                xn[j] = xp[(long)((tg + 1) * 4 + j) * ED];
            }
        }
        #pragma unroll
        for (int j = 0; j < 4; ++j) {
            const int t = tg * 4 + j;
            float dlt = da[j], xv = xa[j];
            float dx = dlt * xv;
            float acc = dvec * xv;
            const float4* Bs4 = reinterpret_cast<const float4*>(&Bs[t * NS]);
            const float4* Cs4 = reinterpret_cast<const float4*>(&Cs[t * NS]);
            #pragma unroll
            for (int k = 0; k < 4; ++k) {
                float4 b4 = Bs4[k];
                float4 c4 = Cs4[k];
                h[4*k+0] = fmaf(EXP2F(dlt * A2[4*k+0]), h[4*k+0], dx * b4.x);
                acc = fmaf(h[4*k+0], c4.x, acc);
                h[4*k+1] = fmaf(EXP2F(dlt * A2[4*k+1]), h[4*k+1], dx * b4.y);
                acc = fmaf(h[4*k+1], c4.y, acc);
                h[4*k+2] = fmaf(EXP2F(dlt * A2[4*k+2]), h[4*k+2], dx * b4.z);
                acc = fmaf(h[4*k+2], c4.z, acc);
                h[4*k+3] = fmaf(EXP2F(dlt * A2[4*k+3]), h[4*k+3], dx * b4.w);
                acc = fmaf(h[4*k+3], c4.w, acc);
            }
            yp[(long)t * ED] = acc;
        }
        #pragma unroll
        for (int j = 0; j < 4; ++j) { da[j] = dn[j]; xa[j] = xn[j]; }
    }
}

// ---------------- fallback (tiny workspace): fully sequential ----------------
__global__ __launch_bounds__(EDG) void ssm_fallback(
    const float* __restrict__ x, const float* __restrict__ dl,
    const float* __restrict__ A, const float* __restrict__ B,
    const float* __restrict__ C, const float* __restrict__ Dv,
    float* __restrict__ y)
{
    const int g = blockIdx.x, b = blockIdx.y;
    const int ed = g * EDG + threadIdx.x;

    float A2[NS];
    {
        const float4* Ap = reinterpret_cast<const float4*>(A + (long)ed * NS);
        #pragma unroll
        for (int k = 0; k < 4; ++k) {
            float4 a4 = Ap[k];
            A2[4*k+0] = a4.x * LOG2E; A2[4*k+1] = a4.y * LOG2E;
            A2[4*k+2] = a4.z * LOG2E; A2[4*k+3] = a4.w * LOG2E;
        }
    }
    float h[NS];
    #pragma unroll
    for (int n = 0; n < NS; ++n) h[n] = 0.f;
    const float dvec = Dv[ed];

    for (int t = 0; t < SEQ; ++t) {
        const long tb = (long)b * SEQ + t;
        float dlt = dl[tb * ED + ed];
        float xv  = x[tb * ED + ed];
        float dx = dlt * xv;
        float acc = dvec * xv;
        const float4* Bp = reinterpret_cast<const float4*>(B + tb * NS);
        const float4* Cp = reinterpret_cast<const float4*>(C + tb * NS);
        #pragma unroll
        for (int k = 0; k < 4; ++k) {
            float4 b4 = Bp[k];
            float4 c4 = Cp[k];
            h[4*k+0] = fmaf(EXP2F(dlt * A2[4*k+0]), h[4*k+0], dx * b4.x);
            acc = fmaf(h[4*k+0], c4.x, acc);
            h[4*k+1] = fmaf(EXP2F(dlt * A2[4*k+1]), h[4*k+1], dx * b4.y);
            acc = fmaf(h[4*k+1], c4.y, acc);
            h[4*k+2] = fmaf(EXP2F(dlt * A2[4*k+2]), h[4*k+2], dx * b4.z);
            acc = fmaf(h[4*k+2], c4.z, acc);
            h[4*k+3] = fmaf(EXP2F(dlt * A2[4*k+3]), h[4*k+3], dx * b4.w);
            acc = fmaf(h[4*k+3], c4.w, acc);
        }
        y[tb * ED + ed] = acc;
    }
}

extern "C" void kernel_launch(void* const* d_in, const int* in_sizes, int n_in,
                              void* d_out, int out_size, void* d_ws, size_t ws_size,
                              hipStream_t stream) {
    const float* x  = (const float*)d_in[0];
    const float* dl = (const float*)d_in[1];
    const float* A  = (const float*)d_in[2];
    const float* B  = (const float*)d_in[3];
    const float* C  = (const float*)d_in[4];
    const float* Dv = (const float*)d_in[5];
    float* y = (float*)d_out;

    const size_t qElems = (size_t)NC * BATCH * ED * NS;   // 2M floats
    const size_t dElems = (size_t)NC * BATCH * ED;        // 128K floats
    const size_t need = (2 * qElems + dElems) * sizeof(float);  // ~16.5 MB

    if (ws_size >= need) {
        float* Q     = (float*)d_ws;
        float* Hprev = Q + qElems;
        float* Dsum  = Hprev + qElems;
        ssm_pass1<<<dim3(NC, NEG, BATCH), EDG, 0, stream>>>(x, dl, A, B, Q, Dsum);
        ssm_pass2<<<(BATCH * ED * NS) / 128, 128, 0, stream>>>(A, Q, Dsum, Hprev);
        ssm_pass3<<<dim3(NC, NEG, BATCH), EDG, 0, stream>>>(x, dl, A, B, C, Dv, Hprev, y);
    } else {
        ssm_fallback<<<dim3(NEG, BATCH), EDG, 0, stream>>>(x, dl, A, B, C, Dv, y);
    }
}